// Round 5
// baseline (1204.820 us; speedup 1.0000x reference)
//
#include <hip/hip_runtime.h>

#define NN 50000
#define NE 800000
#define NG 512
#define F0 92
#define FF 64
#define NB 41
#define HH 128
#define NBLK_SCAN 196   // ceil(NN/256)
#define NBATCH (NE / 64)

typedef float f4 __attribute__((ext_vector_type(4)));
typedef float f4u __attribute__((ext_vector_type(4), aligned(4)));

__device__ __forceinline__ float softplusf(float x) {
    return fmaxf(x, 0.f) + __logf(1.f + __expf(-fabsf(x)));
}
__device__ __forceinline__ float sigmoidf(float x) {
    return __fdividef(1.f, 1.f + __expf(-x));
}

// ---------------- sort-by-src ----------------

__global__ __launch_bounds__(256) void hist_kernel(const int* __restrict__ ei,
                                                   int* __restrict__ cnt)
{
    for (int e = blockIdx.x * 256 + threadIdx.x; e < NE; e += gridDim.x * 256)
        atomicAdd(&cnt[ei[e]], 1);
}

__global__ __launch_bounds__(256) void scan1_kernel(const int* __restrict__ cnt,
                                                    int* __restrict__ bsum)
{
    __shared__ int sd[256];
    const int t = threadIdx.x;
    const int idx = blockIdx.x * 256 + t;
    sd[t] = (idx < NN) ? cnt[idx] : 0;
    __syncthreads();
    for (int s = 128; s > 0; s >>= 1) {
        if (t < s) sd[t] += sd[t + s];
        __syncthreads();
    }
    if (t == 0) bsum[blockIdx.x] = sd[0];
}

__global__ __launch_bounds__(256) void scan2_kernel(int* __restrict__ bsum,
                                                    int* __restrict__ rowptr)
{
    __shared__ int sd[256];
    const int t = threadIdx.x;
    const int v = (t < NBLK_SCAN) ? bsum[t] : 0;
    sd[t] = v;
    __syncthreads();
    for (int off = 1; off < 256; off <<= 1) {
        int a = (t >= off) ? sd[t - off] : 0;
        __syncthreads();
        sd[t] += a;
        __syncthreads();
    }
    if (t < NBLK_SCAN) bsum[t] = sd[t] - v;
    if (t == 255) rowptr[NN] = sd[255];
}

__global__ __launch_bounds__(256) void scan3_kernel(const int* __restrict__ cnt,
                                                    const int* __restrict__ bsum,
                                                    int* __restrict__ rowptr,
                                                    int* __restrict__ cursor)
{
    __shared__ int sd[256];
    const int t = threadIdx.x;
    const int idx = blockIdx.x * 256 + t;
    const int v = (idx < NN) ? cnt[idx] : 0;
    sd[t] = v;
    __syncthreads();
    for (int off = 1; off < 256; off <<= 1) {
        int a = (t >= off) ? sd[t - off] : 0;
        __syncthreads();
        sd[t] += a;
        __syncthreads();
    }
    if (idx < NN) {
        const int ex = bsum[blockIdx.x] + sd[t] - v;
        rowptr[idx] = ex;
        cursor[idx] = ex;
    }
}

// writes perm[pos] = original edge id, srcS[pos], dstS[pos]
__global__ __launch_bounds__(256) void scatter_kernel(const int* __restrict__ ei,
                                                      int* __restrict__ cursor,
                                                      int* __restrict__ perm,
                                                      int* __restrict__ srcS,
                                                      int* __restrict__ dstS)
{
    for (int e = blockIdx.x * 256 + threadIdx.x; e < NE; e += gridDim.x * 256) {
        const int s = ei[e];
        const int pos = atomicAdd(&cursor[s], 1);
        perm[pos] = e;
        srcS[pos] = s;
        dstS[pos] = ei[NE + e];
    }
}

// eaT[k][pos] = ea[perm[pos]][k]  (writes coalesced over pos)
__global__ __launch_bounds__(256) void tr_kernel(const float* __restrict__ ea,
                                                 const int* __restrict__ perm,
                                                 float* __restrict__ eaT)
{
    const int pos = blockIdx.x * 256 + threadIdx.x;
    if (pos >= NE) return;
    const float* row = ea + (size_t)perm[pos] * NB;
#pragma unroll
    for (int k = 0; k < NB; ++k) eaT[(size_t)k * NE + pos] = row[k];
}

// ---------------- network ----------------

__global__ __launch_bounds__(256) void emb_kernel(
    const float* __restrict__ x, const float* __restrict__ W,
    const float* __restrict__ bias, float* __restrict__ h)
{
    __shared__ float sx[4][F0];
    const int lane = threadIdx.x & 63;
    const int w = threadIdx.x >> 6;
    float wr[F0];
#pragma unroll
    for (int k = 0; k < F0; ++k) wr[k] = W[k * FF + lane];
    const float bv = bias[lane];
    const int nit = NN / 4;
    for (int it = blockIdx.x; it < nit; it += gridDim.x) {
        const int n = it * 4 + w;
        if (lane < 46) {
            sx[w][lane * 2]     = x[n * F0 + lane * 2];
            sx[w][lane * 2 + 1] = x[n * F0 + lane * 2 + 1];
        }
        __syncthreads();
        float acc = bv;
#pragma unroll
        for (int k4 = 0; k4 < F0 / 4; ++k4) {
            float4 q = *(const float4*)&sx[w][k4 * 4];
            acc = fmaf(q.x, wr[k4 * 4 + 0], acc);
            acc = fmaf(q.y, wr[k4 * 4 + 1], acc);
            acc = fmaf(q.z, wr[k4 * 4 + 2], acc);
            acc = fmaf(q.w, wr[k4 * 4 + 3], acc);
        }
        h[n * FF + lane] = acc;
        __syncthreads();
    }
}

__global__ __launch_bounds__(256) void stats_kernel(
    const float* __restrict__ src, float* __restrict__ stats)
{
    __shared__ float sd[2][4][FF];
    const int f = threadIdx.x & 63;
    const int r = threadIdx.x >> 6;
    float s = 0.f, s2 = 0.f;
    for (int n = blockIdx.x * 4 + r; n < NN; n += gridDim.x * 4) {
        float v = src[n * FF + f];
        s += v;
        s2 = fmaf(v, v, s2);
    }
    sd[0][r][f] = s;
    sd[1][r][f] = s2;
    __syncthreads();
    if (threadIdx.x < FF) {
        float ts = sd[0][0][f] + sd[0][1][f] + sd[0][2][f] + sd[0][3][f];
        float t2 = sd[1][0][f] + sd[1][1][f] + sd[1][2][f] + sd[1][3][f];
        atomicAdd(&stats[f], ts);
        atomicAdd(&stats[FF + f], t2);
    }
}

__global__ void finalize_kernel(const float* __restrict__ g, const float* __restrict__ b,
                                float* __restrict__ stats)
{
    const int f = threadIdx.x;
    const float inv = 1.f / (float)NN;
    float mean = stats[f] * inv;
    float var = stats[FF + f] * inv - mean * mean;
    float rstd = rsqrtf(var + 1e-5f);
    float A = rstd * g[f];
    stats[2 * FF + f] = A;
    stats[3 * FF + f] = fmaf(-mean, A, b[f]);
}

// wT[i][k][f] : f<64 -> gate col f of W-row (128+k); f>=64 -> core col (f-64)
__global__ __launch_bounds__(256) void prep_kernel(
    const float* __restrict__ lnfW, const float* __restrict__ lnsW,
    float* __restrict__ wT)
{
    const int total = 3 * NB * 128;
    for (int idx = blockIdx.x * 256 + threadIdx.x; idx < total; idx += gridDim.x * 256) {
        const int f = idx & 127;
        const int k = (idx >> 7) % NB;
        const int i = idx / (128 * NB);
        const float* W = (f < FF ? lnfW : lnsW) + (size_t)i * 169 * FF;
        wT[idx] = W[(2 * FF + k) * FF + (f & 63)];
    }
}

// xn = bn1(h); pS[n*128+2f+{0,1}] = xn@{Wf,Ws}_src + {bf,bs}; pD likewise (dst rows, no bias)
__global__ __launch_bounds__(256) void node_kernel(
    const float* __restrict__ h, const float* __restrict__ stats,
    const float* __restrict__ Wf, const float* __restrict__ Ws,
    const float* __restrict__ bf, const float* __restrict__ bs,
    float* __restrict__ xn, float* __restrict__ pS, float* __restrict__ pD)
{
    __shared__ float sx[4][FF];
    const int lane = threadIdx.x & 63;
    const int w = threadIdx.x >> 6;
    const float* W = (w < 2) ? Wf : Ws;
    const int rowbase = (w & 1) * FF;
    float wr[FF];
#pragma unroll
    for (int k = 0; k < FF; ++k) wr[k] = W[(rowbase + k) * FF + lane];
    const float A = stats[2 * FF + lane];
    const float B = stats[3 * FF + lane];
    float bias = 0.f;
    if (w == 0) bias = bf[lane];
    if (w == 2) bias = bs[lane];
    float* outp = ((w & 1) ? pD : pS) + ((w >> 1) & 1);
    for (int n = blockIdx.x; n < NN; n += gridDim.x) {
        const float xv = fmaf(h[n * FF + lane], A, B);
        if (w == 0) xn[n * FF + lane] = xv;
        sx[w][lane] = xv;
        __syncthreads();
        float acc = bias;
#pragma unroll
        for (int k4 = 0; k4 < FF / 4; ++k4) {
            float4 q = *(const float4*)&sx[w][k4 * 4];
            acc = fmaf(q.x, wr[k4 * 4 + 0], acc);
            acc = fmaf(q.y, wr[k4 * 4 + 1], acc);
            acc = fmaf(q.z, wr[k4 * 4 + 2], acc);
            acc = fmaf(q.w, wr[k4 * 4 + 3], acc);
        }
        outp[(size_t)n * 128 + 2 * lane] = acc;
        __syncthreads();
    }
}

// lane = edge. 64 sorted edges per wave. Weights broadcast from LDS.
// f-tiles of 16 (32 accs). Epilogue: m -> LDS, 16 steps of (4e x 16f),
// segmented sum over sorted src runs, run-head lanes flush via atomicAdd.
__global__ __launch_bounds__(256) __attribute__((amdgpu_waves_per_eu(4, 4)))
void edge_kernel(
    const float* __restrict__ eaT, const int* __restrict__ srcS,
    const int* __restrict__ dstS, const float* __restrict__ wT,
    const float* __restrict__ pS, const float* __restrict__ pD,
    float* __restrict__ agg)
{
    __shared__ float wlds[NB * 128];        // 21 KB
    __shared__ float mld[4][64 * 17 + 4];   // per-wave m staging, padded rows
    __shared__ int   sld[4][64];            // per-wave src staging
    const int t = threadIdx.x;
    const int lane = t & 63;
    const int w = t >> 6;
    for (int i = t; i < NB * 128; i += 256) wlds[i] = wT[i];
    __syncthreads();

    const int nw = (gridDim.x * blockDim.x) >> 6;
    const int gw = (blockIdx.x * blockDim.x + t) >> 6;
    const int le = lane >> 4, lf = lane & 15;

    for (int b = gw; b < NBATCH; b += nw) {
        const int pos = b * 64 + lane;
        const int srcv = srcS[pos];
        const int dstv = dstS[pos];
        sld[w][lane] = srcv;
        float e[NB];
#pragma unroll
        for (int k = 0; k < NB; ++k) e[k] = eaT[(size_t)k * NE + pos];

        for (int tile = 0; tile < 4; ++tile) {
            const int f0 = tile * 16;
            float accF[16], accS[16];
#pragma unroll
            for (int j = 0; j < 16; ++j) { accF[j] = 0.f; accS[j] = 0.f; }
#pragma unroll
            for (int k = 0; k < NB; ++k) {
                const f4* wg = (const f4*)&wlds[k * 128 + f0];
                const f4* wc = (const f4*)&wlds[k * 128 + FF + f0];
#pragma unroll
                for (int q = 0; q < 4; ++q) {
                    const f4 g = wg[q], c = wc[q];
                    accF[4 * q + 0] = fmaf(e[k], g.x, accF[4 * q + 0]);
                    accF[4 * q + 1] = fmaf(e[k], g.y, accF[4 * q + 1]);
                    accF[4 * q + 2] = fmaf(e[k], g.z, accF[4 * q + 2]);
                    accF[4 * q + 3] = fmaf(e[k], g.w, accF[4 * q + 3]);
                    accS[4 * q + 0] = fmaf(e[k], c.x, accS[4 * q + 0]);
                    accS[4 * q + 1] = fmaf(e[k], c.y, accS[4 * q + 1]);
                    accS[4 * q + 2] = fmaf(e[k], c.z, accS[4 * q + 2]);
                    accS[4 * q + 3] = fmaf(e[k], c.w, accS[4 * q + 3]);
                }
            }
            // m = sigmoid(gate + pSf + pDf) * softplus(core + pSs + pDs) -> LDS
            const float* pSr = pS + (size_t)srcv * 128 + f0 * 2;
            const float* pDr = pD + (size_t)dstv * 128 + f0 * 2;
#pragma unroll
            for (int q = 0; q < 8; ++q) {
                const f4u sv = *(const f4u*)(pSr + 4 * q);
                const f4u dv = *(const f4u*)(pDr + 4 * q);
                const float mF0 = accF[2 * q]     + sv.x + dv.x;
                const float mS0 = accS[2 * q]     + sv.y + dv.y;
                const float mF1 = accF[2 * q + 1] + sv.z + dv.z;
                const float mS1 = accS[2 * q + 1] + sv.w + dv.w;
                mld[w][lane * 17 + 2 * q]     = sigmoidf(mF0) * softplusf(mS0);
                mld[w][lane * 17 + 2 * q + 1] = sigmoidf(mF1) * softplusf(mS1);
            }
            // 16 steps of (4 edges x 16 features)
            for (int s = 0; s < 16; ++s) {
                const int eidx = s * 4 + le;
                float v = mld[w][eidx * 17 + lf];
                const int sA = sld[w][eidx];
                const int sB = (le <= 2) ? sld[w][eidx + 1] : -1;
                const int sC = (le <= 1) ? sld[w][eidx + 2] : -1;
                const float t1 = __shfl_down(v, 16);
                if (sB == sA) v += t1;
                const float t2 = __shfl_down(v, 32);
                if (sC == sA) v += t2;
                const bool head = (le == 0) || (sld[w][eidx - 1] != sA);
                if (head) unsafeAtomicAdd(&agg[(size_t)sA * FF + f0 + lf], v);
            }
        }
    }
}

__global__ __launch_bounds__(256) void update_kernel(
    const float* __restrict__ agg, const float* __restrict__ xn,
    const float* __restrict__ stats, float* __restrict__ h,
    const int* __restrict__ batch, float* __restrict__ pool,
    float* __restrict__ pcnt, const int do_pool)
{
    const int total = NN * FF;
    for (int idx = blockIdx.x * blockDim.x + threadIdx.x; idx < total;
         idx += gridDim.x * blockDim.x) {
        const int f = idx & 63;
        const int n = idx >> 6;
        const float A = stats[2 * FF + f];
        const float B = stats[3 * FF + f];
        const float v = softplusf(fmaf(agg[idx], A, B) + xn[idx]);
        if (do_pool) {
            const int g = batch[n];
            unsafeAtomicAdd(&pool[g * FF + f], v);
            if (f == 0) unsafeAtomicAdd(&pcnt[g], 1.f);
        } else {
            h[idx] = v;
        }
    }
}

__global__ __launch_bounds__(128) void readout_kernel(
    const float* __restrict__ pool, const float* __restrict__ pcnt,
    const float* __restrict__ fc1W, const float* __restrict__ fc1b,
    const float* __restrict__ outW, const float* __restrict__ outb,
    float* __restrict__ out)
{
    __shared__ float sp[FF];
    __shared__ float red[2];
    const int g = blockIdx.x;
    const int t = threadIdx.x;
    if (t < FF) {
        const float c = fmaxf(pcnt[g], 1.f);
        sp[t] = softplusf(pool[g * FF + t] / c);
    }
    __syncthreads();
    float a = fc1b[t];
#pragma unroll
    for (int k = 0; k < FF; ++k) a = fmaf(sp[k], fc1W[k * HH + t], a);
    float o = softplusf(a) * outW[t];
#pragma unroll
    for (int off = 32; off > 0; off >>= 1) o += __shfl_down(o, off, 64);
    if ((t & 63) == 0) red[t >> 6] = o;
    __syncthreads();
    if (t == 0) out[g] = red[0] + red[1] + outb[0];
}

extern "C" void kernel_launch(void* const* d_in, const int* in_sizes, int n_in,
                              void* d_out, int out_size, void* d_ws, size_t ws_size,
                              hipStream_t stream)
{
    const float* x     = (const float*)d_in[0];
    const int*   ei    = (const int*)  d_in[1];
    const float* ea    = (const float*)d_in[2];
    const int*   batch = (const int*)  d_in[3];
    const float* embW  = (const float*)d_in[4];
    const float* embb  = (const float*)d_in[5];
    const float* bn1g  = (const float*)d_in[6];
    const float* bn1b  = (const float*)d_in[7];
    const float* bn2g  = (const float*)d_in[8];
    const float* bn2b  = (const float*)d_in[9];
    const float* lnfW  = (const float*)d_in[10];
    const float* lnfb  = (const float*)d_in[11];
    const float* lnsW  = (const float*)d_in[12];
    const float* lnsb  = (const float*)d_in[13];
    const float* fc1W  = (const float*)d_in[14];
    const float* fc1b  = (const float*)d_in[15];
    const float* outW  = (const float*)d_in[16];
    const float* outb  = (const float*)d_in[17];

    float* ws    = (float*)d_ws;
    float* h     = ws;
    float* xn    = h    + (size_t)NN * FF;
    float* pS    = xn   + (size_t)NN * FF;          // [NN][128] interleaved f/s
    float* pD    = pS   + (size_t)NN * 128;
    float* agg   = pD   + (size_t)NN * 128;
    float* stats = agg  + (size_t)NN * FF;
    float* pool  = stats + 4 * FF;
    float* pcnt  = pool + (size_t)NG * FF;
    float* wT    = pcnt + NG;                       // [3][41][128]
    int*   cnt    = (int*)(wT + 3 * NB * 128);      // NN
    int*   rowptr = cnt + NN;                       // NN+2
    int*   cursor = rowptr + NN + 2;                // NN
    int*   bsum   = cursor + NN;                    // 256
    int*   perm   = bsum + 256;                     // NE
    int*   srcS   = perm + NE;                      // NE
    int*   dstS   = srcS + NE;                      // NE
    float* eaT    = (float*)(dstS + NE);            // [41][NE]

    // ---- sort by src + permuted transpose of ea (once per call) ----
    hipMemsetAsync(cnt, 0, NN * sizeof(int), stream);
    hist_kernel<<<2048, 256, 0, stream>>>(ei, cnt);
    scan1_kernel<<<NBLK_SCAN, 256, 0, stream>>>(cnt, bsum);
    scan2_kernel<<<1, 256, 0, stream>>>(bsum, rowptr);
    scan3_kernel<<<NBLK_SCAN, 256, 0, stream>>>(cnt, bsum, rowptr, cursor);
    scatter_kernel<<<2048, 256, 0, stream>>>(ei, cursor, perm, srcS, dstS);
    tr_kernel<<<(NE + 255) / 256, 256, 0, stream>>>(ea, perm, eaT);

    hipMemsetAsync(pool, 0, (NG * FF + NG) * sizeof(float), stream);
    prep_kernel<<<62, 256, 0, stream>>>(lnfW, lnsW, wT);
    emb_kernel<<<1024, 256, 0, stream>>>(x, embW, embb, h);

    for (int i = 0; i < 3; ++i) {
        const float* Wf  = lnfW + (size_t)i * 169 * FF;
        const float* Wsp = lnsW + (size_t)i * 169 * FF;
        hipMemsetAsync(stats, 0, 2 * FF * sizeof(float), stream);
        stats_kernel<<<256, 256, 0, stream>>>(h, stats);
        finalize_kernel<<<1, 64, 0, stream>>>(bn1g + i * FF, bn1b + i * FF, stats);
        node_kernel<<<1024, 256, 0, stream>>>(h, stats, Wf, Wsp,
                                              lnfb + i * FF, lnsb + i * FF, xn, pS, pD);
        hipMemsetAsync(agg, 0, (size_t)NN * FF * sizeof(float), stream);
        edge_kernel<<<NBATCH / 4, 256, 0, stream>>>(eaT, srcS, dstS,
                                                    wT + (size_t)i * NB * 128, pS, pD, agg);
        hipMemsetAsync(stats, 0, 2 * FF * sizeof(float), stream);
        stats_kernel<<<256, 256, 0, stream>>>(agg, stats);
        finalize_kernel<<<1, 64, 0, stream>>>(bn2g + i * FF, bn2b + i * FF, stats);
        update_kernel<<<2048, 256, 0, stream>>>(agg, xn, stats, h, batch, pool, pcnt,
                                                (i == 2) ? 1 : 0);
    }
    readout_kernel<<<NG, HH, 0, stream>>>(pool, pcnt, fc1W, fc1b, outW, outb, (float*)d_out);
}

// Round 6
// 950.303 us; speedup vs baseline: 1.2678x; 1.2678x over previous
//
#include <hip/hip_runtime.h>
#include <hip/hip_bf16.h>

#define NN 50000
#define NE 800000
#define NG 512
#define F0 92
#define FF 64
#define NB 41
#define HH 128
#define NBLK_SCAN 196          // ceil(NN/256)
#define NBATCH (NE / 64)
#define WBSZ (2 * 8 * 64 * 8)  // per-conv packed edge-weight elements (ushort)

typedef __attribute__((ext_vector_type(4))) float f32x4;
typedef __attribute__((ext_vector_type(8))) short bf16x8;

__device__ __forceinline__ float softplusf(float x) {
    return fmaxf(x, 0.f) + __logf(1.f + __expf(-fabsf(x)));
}
__device__ __forceinline__ float sigmoidf(float x) {
    return __fdividef(1.f, 1.f + __expf(-x));
}
__device__ __forceinline__ ushort f2bf(float v) {
    __hip_bfloat16 b = __float2bfloat16(v);   // RTN
    return *reinterpret_cast<ushort*>(&b);
}

// ---------------- sort-by-src + bf16 fragment packing ----------------

__global__ __launch_bounds__(256) void hist_kernel(const int* __restrict__ ei,
                                                   int* __restrict__ cnt)
{
    for (int e = blockIdx.x * 256 + threadIdx.x; e < NE; e += gridDim.x * 256)
        atomicAdd(&cnt[ei[e]], 1);
}

__global__ __launch_bounds__(256) void scan1_kernel(const int* __restrict__ cnt,
                                                    int* __restrict__ bsum)
{
    __shared__ int sd[256];
    const int t = threadIdx.x;
    const int idx = blockIdx.x * 256 + t;
    sd[t] = (idx < NN) ? cnt[idx] : 0;
    __syncthreads();
    for (int s = 128; s > 0; s >>= 1) {
        if (t < s) sd[t] += sd[t + s];
        __syncthreads();
    }
    if (t == 0) bsum[blockIdx.x] = sd[0];
}

__global__ __launch_bounds__(256) void scan2_kernel(int* __restrict__ bsum)
{
    __shared__ int sd[256];
    const int t = threadIdx.x;
    const int v = (t < NBLK_SCAN) ? bsum[t] : 0;
    sd[t] = v;
    __syncthreads();
    for (int off = 1; off < 256; off <<= 1) {
        int a = (t >= off) ? sd[t - off] : 0;
        __syncthreads();
        sd[t] += a;
        __syncthreads();
    }
    if (t < NBLK_SCAN) bsum[t] = sd[t] - v;   // exclusive
}

__global__ __launch_bounds__(256) void scan3_kernel(const int* __restrict__ cnt,
                                                    const int* __restrict__ bsum,
                                                    int* __restrict__ cursor)
{
    __shared__ int sd[256];
    const int t = threadIdx.x;
    const int idx = blockIdx.x * 256 + t;
    const int v = (idx < NN) ? cnt[idx] : 0;
    sd[t] = v;
    __syncthreads();
    for (int off = 1; off < 256; off <<= 1) {
        int a = (t >= off) ? sd[t - off] : 0;
        __syncthreads();
        sd[t] += a;
        __syncthreads();
    }
    if (idx < NN) cursor[idx] = bsum[blockIdx.x] + sd[t] - v;
}

// sorted position + srcS/dstS + bf16 A-fragment packing of ea
// eaP layout: [group][kstep][lane][j] bf16 where edge = group*16 + (lane&15),
// k = kstep*32 + (lane>>4)*8 + j  (zero-padded k>=41)
__global__ __launch_bounds__(256) void scatter_kernel(const int* __restrict__ ei,
                                                      const float* __restrict__ ea,
                                                      int* __restrict__ cursor,
                                                      int* __restrict__ srcS,
                                                      int* __restrict__ dstS,
                                                      ushort* __restrict__ eaP)
{
    for (int e = blockIdx.x * 256 + threadIdx.x; e < NE; e += gridDim.x * 256) {
        const int s = ei[e];
        const int d = ei[NE + e];
        const int pos = atomicAdd(&cursor[s], 1);
        srcS[pos] = s;
        dstS[pos] = d;
        const float* row = ea + (size_t)e * NB;
        const int gg = pos >> 4, rw = pos & 15;
#pragma unroll
        for (int t2 = 0; t2 < 2; ++t2)
#pragma unroll
            for (int lg = 0; lg < 4; ++lg) {
                ushort buf[8] __attribute__((aligned(16)));
#pragma unroll
                for (int j = 0; j < 8; ++j) {
                    const int k = t2 * 32 + lg * 8 + j;
                    buf[j] = (k < NB) ? f2bf(row[k]) : (ushort)0;
                }
                *(int4*)&eaP[(((size_t)gg * 2 + t2) * 64 + lg * 16 + rw) * 8] =
                    *(const int4*)buf;
            }
    }
}

// packed B-fragments: wB[conv][kstep][ntile][lane][j] bf16
// B[k][col]: k = kstep*32 + (lane>>4)*8 + j, col = ntile*16 + (lane&15)
// ntile 0..3 -> gate (Wf), 4..7 -> core (Ws)
__global__ __launch_bounds__(256) void prep_kernel(
    const float* __restrict__ lnfW, const float* __restrict__ lnsW,
    ushort* __restrict__ wB)
{
    const int total = 3 * WBSZ;
    for (int idx = blockIdx.x * 256 + threadIdx.x; idx < total; idx += gridDim.x * 256) {
        const int j = idx & 7;
        const int lane = (idx >> 3) & 63;
        const int nt = (idx >> 9) & 7;
        const int t2 = (idx >> 12) & 1;
        const int i = idx >> 13;
        const int k = t2 * 32 + (lane >> 4) * 8 + j;
        const int col = (nt & 3) * 16 + (lane & 15);
        const float* W = (nt < 4 ? lnfW : lnsW) + (size_t)i * 169 * FF;
        wB[idx] = (k < NB) ? f2bf(W[(2 * FF + k) * FF + col]) : (ushort)0;
    }
}

// ---------------- network ----------------

// h = x @ embW + embb, fused column stats for bn1 of conv0
__global__ __launch_bounds__(256) void emb_kernel(
    const float* __restrict__ x, const float* __restrict__ W,
    const float* __restrict__ bias, float* __restrict__ h,
    float* __restrict__ stats0)
{
    __shared__ float sx[4][F0];
    __shared__ float sdr[2][4][FF];
    const int lane = threadIdx.x & 63;
    const int w = threadIdx.x >> 6;
    float wr[F0];
#pragma unroll
    for (int k = 0; k < F0; ++k) wr[k] = W[k * FF + lane];
    const float bv = bias[lane];
    float s = 0.f, s2 = 0.f;
    const int nit = NN / 4;
    for (int it = blockIdx.x; it < nit; it += gridDim.x) {
        const int n = it * 4 + w;
        if (lane < 46) {
            sx[w][lane * 2]     = x[n * F0 + lane * 2];
            sx[w][lane * 2 + 1] = x[n * F0 + lane * 2 + 1];
        }
        __syncthreads();
        float acc = bv;
#pragma unroll
        for (int k4 = 0; k4 < F0 / 4; ++k4) {
            float4 q = *(const float4*)&sx[w][k4 * 4];
            acc = fmaf(q.x, wr[k4 * 4 + 0], acc);
            acc = fmaf(q.y, wr[k4 * 4 + 1], acc);
            acc = fmaf(q.z, wr[k4 * 4 + 2], acc);
            acc = fmaf(q.w, wr[k4 * 4 + 3], acc);
        }
        h[n * FF + lane] = acc;
        s += acc;
        s2 = fmaf(acc, acc, s2);
        __syncthreads();
    }
    sdr[0][w][lane] = s;
    sdr[1][w][lane] = s2;
    __syncthreads();
    if (threadIdx.x < FF) {
        const int f = threadIdx.x;
        atomicAdd(&stats0[f],      sdr[0][0][f] + sdr[0][1][f] + sdr[0][2][f] + sdr[0][3][f]);
        atomicAdd(&stats0[FF + f], sdr[1][0][f] + sdr[1][1][f] + sdr[1][2][f] + sdr[1][3][f]);
    }
}

// column sums / sumsq (used for agg / bn2)
__global__ __launch_bounds__(256) void stats_kernel(
    const float* __restrict__ src, float* __restrict__ stats)
{
    __shared__ float sd[2][4][FF];
    const int f = threadIdx.x & 63;
    const int r = threadIdx.x >> 6;
    float s = 0.f, s2 = 0.f;
    for (int n = blockIdx.x * 4 + r; n < NN; n += gridDim.x * 4) {
        float v = src[n * FF + f];
        s += v;
        s2 = fmaf(v, v, s2);
    }
    sd[0][r][f] = s;
    sd[1][r][f] = s2;
    __syncthreads();
    if (threadIdx.x < FF) {
        atomicAdd(&stats[f],      sd[0][0][f] + sd[0][1][f] + sd[0][2][f] + sd[0][3][f]);
        atomicAdd(&stats[FF + f], sd[1][0][f] + sd[1][1][f] + sd[1][2][f] + sd[1][3][f]);
    }
}

__global__ void finalize_kernel(const float* __restrict__ g, const float* __restrict__ b,
                                float* __restrict__ stats)
{
    const int f = threadIdx.x;
    const float inv = 1.f / (float)NN;
    float mean = stats[f] * inv;
    float var = stats[FF + f] * inv - mean * mean;
    float rstd = rsqrtf(var + 1e-5f);
    float A = rstd * g[f];
    stats[2 * FF + f] = A;
    stats[3 * FF + f] = fmaf(-mean, A, b[f]);
}

// xn = bn1(h); pS[n*128+2f+{0,1}] = xn@{Wf,Ws}_src + {bf,bs}; pD likewise (dst rows)
__global__ __launch_bounds__(256) void node_kernel(
    const float* __restrict__ h, const float* __restrict__ stats,
    const float* __restrict__ Wf, const float* __restrict__ Ws,
    const float* __restrict__ bf, const float* __restrict__ bs,
    float* __restrict__ xn, float* __restrict__ pS, float* __restrict__ pD)
{
    __shared__ float sx[4][FF];
    const int lane = threadIdx.x & 63;
    const int w = threadIdx.x >> 6;
    const float* W = (w < 2) ? Wf : Ws;
    const int rowbase = (w & 1) * FF;
    float wr[FF];
#pragma unroll
    for (int k = 0; k < FF; ++k) wr[k] = W[(rowbase + k) * FF + lane];
    const float A = stats[2 * FF + lane];
    const float B = stats[3 * FF + lane];
    float bias = 0.f;
    if (w == 0) bias = bf[lane];
    if (w == 2) bias = bs[lane];
    float* outp = ((w & 1) ? pD : pS) + ((w >> 1) & 1);
    for (int n = blockIdx.x; n < NN; n += gridDim.x) {
        const float xv = fmaf(h[n * FF + lane], A, B);
        if (w == 0) xn[n * FF + lane] = xv;
        sx[w][lane] = xv;
        __syncthreads();
        float acc = bias;
#pragma unroll
        for (int k4 = 0; k4 < FF / 4; ++k4) {
            float4 q = *(const float4*)&sx[w][k4 * 4];
            acc = fmaf(q.x, wr[k4 * 4 + 0], acc);
            acc = fmaf(q.y, wr[k4 * 4 + 1], acc);
            acc = fmaf(q.z, wr[k4 * 4 + 2], acc);
            acc = fmaf(q.w, wr[k4 * 4 + 3], acc);
        }
        outp[(size_t)n * 128 + 2 * lane] = acc;
        __syncthreads();
    }
}

// MFMA edge kernel: 64 sorted edges per wave-batch, 4 groups of 16 (M=16).
// gate/core via v_mfma_f32_16x16x32_bf16, K=64 in 2 steps. Epilogue adds fp32
// node projections, m=sig*softplus, stage to LDS, segmented sum over sorted
// src runs, per-run-head atomicAdd.
__global__ __launch_bounds__(256) __attribute__((amdgpu_waves_per_eu(4, 4)))
void edge_kernel(const ushort* __restrict__ eaP, const int* __restrict__ srcS,
                 const int* __restrict__ dstS, const ushort* __restrict__ wB,
                 const float* __restrict__ pS, const float* __restrict__ pD,
                 float* __restrict__ agg)
{
    __shared__ ushort wlds[WBSZ];           // 16 KB packed B-fragments
    __shared__ float  mld[4][64 * 17 + 4];  // per-wave m staging
    __shared__ int    sld[4][64];
    __shared__ int    dld[4][64];
    const int t = threadIdx.x, lane = t & 63, w = t >> 6;
    for (int i = t; i < WBSZ / 8; i += 256)
        ((int4*)wlds)[i] = ((const int4*)wB)[i];
    __syncthreads();
    const int le = lane >> 4, lf = lane & 15;
    const int nw = (gridDim.x * 256) >> 6;
    const int gw = (blockIdx.x * 256 + t) >> 6;

    for (int b = gw; b < NBATCH; b += nw) {
        const int pos = b * 64 + lane;
        sld[w][lane] = srcS[pos];
        dld[w][lane] = dstS[pos];
        bf16x8 af[4][2];
#pragma unroll
        for (int g = 0; g < 4; ++g)
#pragma unroll
            for (int t2 = 0; t2 < 2; ++t2)
                af[g][t2] = *(const bf16x8*)&eaP[(((size_t)(b * 4 + g) * 2 + t2) * 64 + lane) * 8];

#pragma unroll
        for (int p = 0; p < 4; ++p) {
            const bf16x8 bG0 = *(const bf16x8*)&wlds[((0 * 8 + p) * 64 + lane) * 8];
            const bf16x8 bG1 = *(const bf16x8*)&wlds[((1 * 8 + p) * 64 + lane) * 8];
            const bf16x8 bC0 = *(const bf16x8*)&wlds[((0 * 8 + p + 4) * 64 + lane) * 8];
            const bf16x8 bC1 = *(const bf16x8*)&wlds[((1 * 8 + p + 4) * 64 + lane) * 8];
            const int f = p * 16 + lf;
#pragma unroll
            for (int g = 0; g < 4; ++g) {
                f32x4 aG = {0.f, 0.f, 0.f, 0.f}, aC = {0.f, 0.f, 0.f, 0.f};
                aG = __builtin_amdgcn_mfma_f32_16x16x32_bf16(af[g][0], bG0, aG, 0, 0, 0);
                aG = __builtin_amdgcn_mfma_f32_16x16x32_bf16(af[g][1], bG1, aG, 0, 0, 0);
                aC = __builtin_amdgcn_mfma_f32_16x16x32_bf16(af[g][0], bC0, aC, 0, 0, 0);
                aC = __builtin_amdgcn_mfma_f32_16x16x32_bf16(af[g][1], bC1, aC, 0, 0, 0);
                const int eb = g * 16 + le * 4;   // C/D row = 4*(lane>>4)+r
#pragma unroll
                for (int r = 0; r < 4; ++r) {
                    const int eidx = eb + r;
                    const int sv = sld[w][eidx];
                    const int dv = dld[w][eidx];
                    const float2 s2 = *(const float2*)(pS + (size_t)sv * 128 + 2 * f);
                    const float2 d2 = *(const float2*)(pD + (size_t)dv * 128 + 2 * f);
                    mld[w][eidx * 17 + lf] =
                        sigmoidf(aG[r] + s2.x + d2.x) * softplusf(aC[r] + s2.y + d2.y);
                }
            }
            const int f0 = p * 16;
            for (int s = 0; s < 16; ++s) {
                const int eidx = s * 4 + le;
                float v = mld[w][eidx * 17 + lf];
                const int sA = sld[w][eidx];
                const int sB = (le <= 2) ? sld[w][eidx + 1] : -1;
                const int sC = (le <= 1) ? sld[w][eidx + 2] : -1;
                const float t1 = __shfl_down(v, 16, 64);
                if (sB == sA) v += t1;
                const float t2v = __shfl_down(v, 32, 64);
                if (sC == sA) v += t2v;
                const bool head = (le == 0) || (sld[w][eidx - 1] != sA);
                if (head) unsafeAtomicAdd(&agg[(size_t)sA * FF + f0 + lf], v);
            }
        }
    }
}

// h = softplus(bn2(agg) + xn); fused stats for next conv's bn1; last conv pools
__global__ __launch_bounds__(256) void update_kernel(
    const float* __restrict__ agg, const float* __restrict__ xn,
    const float* __restrict__ stats, float* __restrict__ h,
    const int* __restrict__ batch, float* __restrict__ pool,
    float* __restrict__ pcnt, float* __restrict__ statsNext, const int do_pool)
{
    __shared__ float sdr[2][4][FF];
    float s = 0.f, s2 = 0.f;
    const int total = NN * FF;
    for (int idx = blockIdx.x * blockDim.x + threadIdx.x; idx < total;
         idx += gridDim.x * blockDim.x) {
        const int f = idx & 63;
        const int n = idx >> 6;
        const float A = stats[2 * FF + f];
        const float B = stats[3 * FF + f];
        const float v = softplusf(fmaf(agg[idx], A, B) + xn[idx]);
        if (do_pool) {
            const int g = batch[n];
            unsafeAtomicAdd(&pool[g * FF + f], v);
            if (f == 0) unsafeAtomicAdd(&pcnt[g], 1.f);
        } else {
            h[idx] = v;
            s += v;
            s2 = fmaf(v, v, s2);
        }
    }
    if (!do_pool) {
        const int f = threadIdx.x & 63, r = threadIdx.x >> 6;
        sdr[0][r][f] = s;
        sdr[1][r][f] = s2;
        __syncthreads();
        if (threadIdx.x < FF) {
            atomicAdd(&statsNext[f],      sdr[0][0][f] + sdr[0][1][f] + sdr[0][2][f] + sdr[0][3][f]);
            atomicAdd(&statsNext[FF + f], sdr[1][0][f] + sdr[1][1][f] + sdr[1][2][f] + sdr[1][3][f]);
        }
    }
}

__global__ __launch_bounds__(128) void readout_kernel(
    const float* __restrict__ pool, const float* __restrict__ pcnt,
    const float* __restrict__ fc1W, const float* __restrict__ fc1b,
    const float* __restrict__ outW, const float* __restrict__ outb,
    float* __restrict__ out)
{
    __shared__ float sp[FF];
    __shared__ float red[2];
    const int g = blockIdx.x;
    const int t = threadIdx.x;
    if (t < FF) {
        const float c = fmaxf(pcnt[g], 1.f);
        sp[t] = softplusf(pool[g * FF + t] / c);
    }
    __syncthreads();
    float a = fc1b[t];
#pragma unroll
    for (int k = 0; k < FF; ++k) a = fmaf(sp[k], fc1W[k * HH + t], a);
    float o = softplusf(a) * outW[t];
#pragma unroll
    for (int off = 32; off > 0; off >>= 1) o += __shfl_down(o, off, 64);
    if ((t & 63) == 0) red[t >> 6] = o;
    __syncthreads();
    if (t == 0) out[g] = red[0] + red[1] + outb[0];
}

extern "C" void kernel_launch(void* const* d_in, const int* in_sizes, int n_in,
                              void* d_out, int out_size, void* d_ws, size_t ws_size,
                              hipStream_t stream)
{
    const float* x     = (const float*)d_in[0];
    const int*   ei    = (const int*)  d_in[1];
    const float* ea    = (const float*)d_in[2];
    const int*   batch = (const int*)  d_in[3];
    const float* embW  = (const float*)d_in[4];
    const float* embb  = (const float*)d_in[5];
    const float* bn1g  = (const float*)d_in[6];
    const float* bn1b  = (const float*)d_in[7];
    const float* bn2g  = (const float*)d_in[8];
    const float* bn2b  = (const float*)d_in[9];
    const float* lnfW  = (const float*)d_in[10];
    const float* lnfb  = (const float*)d_in[11];
    const float* lnsW  = (const float*)d_in[12];
    const float* lnsb  = (const float*)d_in[13];
    const float* fc1W  = (const float*)d_in[14];
    const float* fc1b  = (const float*)d_in[15];
    const float* outW  = (const float*)d_in[16];
    const float* outb  = (const float*)d_in[17];

    float* ws      = (float*)d_ws;
    float* h       = ws;
    float* xn      = h   + (size_t)NN * FF;
    float* pS      = xn  + (size_t)NN * FF;      // [NN][128] interleaved gate/core
    float* pD      = pS  + (size_t)NN * 128;
    float* agg     = pD  + (size_t)NN * 128;
    float* pool    = agg + (size_t)NN * FF;
    float* pcnt    = pool + (size_t)NG * FF;
    float* statsB1 = pcnt + NG;                  // 3 x 256
    float* statsB2 = statsB1 + 3 * 256;          // 3 x 256
    int*   cnt     = (int*)(statsB2 + 3 * 256);  // NN
    int*   cursor  = cnt + NN;                   // NN
    int*   bsum    = cursor + NN;                // 256
    int*   srcS    = bsum + 256;                 // NE
    int*   dstS    = srcS + NE;                  // NE
    ushort* wB     = (ushort*)(dstS + NE);       // 3 * WBSZ
    ushort* eaP    = wB + 3 * WBSZ;              // NE * 64 bf16

    // zero: cnt + (pool, pcnt, stats) regions
    hipMemsetAsync(cnt, 0, NN * sizeof(int), stream);
    hipMemsetAsync(pool, 0, (NG * FF + NG + 6 * 256) * sizeof(float), stream);

    hist_kernel<<<2048, 256, 0, stream>>>(ei, cnt);
    scan1_kernel<<<NBLK_SCAN, 256, 0, stream>>>(cnt, bsum);
    scan2_kernel<<<1, 256, 0, stream>>>(bsum);
    scan3_kernel<<<NBLK_SCAN, 256, 0, stream>>>(cnt, bsum, cursor);
    scatter_kernel<<<2048, 256, 0, stream>>>(ei, ea, cursor, srcS, dstS, eaP);
    prep_kernel<<<96, 256, 0, stream>>>(lnfW, lnsW, wB);
    emb_kernel<<<1024, 256, 0, stream>>>(x, embW, embb, h, statsB1);

    for (int i = 0; i < 3; ++i) {
        const float* Wf  = lnfW + (size_t)i * 169 * FF;
        const float* Wsp = lnsW + (size_t)i * 169 * FF;
        float* s1 = statsB1 + (size_t)i * 256;
        float* s2 = statsB2 + (size_t)i * 256;
        finalize_kernel<<<1, 64, 0, stream>>>(bn1g + i * FF, bn1b + i * FF, s1);
        node_kernel<<<1024, 256, 0, stream>>>(h, s1, Wf, Wsp,
                                              lnfb + i * FF, lnsb + i * FF, xn, pS, pD);
        hipMemsetAsync(agg, 0, (size_t)NN * FF * sizeof(float), stream);
        edge_kernel<<<1024, 256, 0, stream>>>(eaP, srcS, dstS, wB + (size_t)i * WBSZ,
                                              pS, pD, agg);
        stats_kernel<<<256, 256, 0, stream>>>(agg, s2);
        finalize_kernel<<<1, 64, 0, stream>>>(bn2g + i * FF, bn2b + i * FF, s2);
        update_kernel<<<2048, 256, 0, stream>>>(agg, xn, s2, h, batch, pool, pcnt,
                                                statsB1 + (size_t)(i + 1 < 3 ? i + 1 : 0) * 256,
                                                (i == 2) ? 1 : 0);
    }
    readout_kernel<<<NG, HH, 0, stream>>>(pool, pcnt, fc1W, fc1b, outW, outb, (float*)d_out);
}

// Round 7
// 948.646 us; speedup vs baseline: 1.2700x; 1.0017x over previous
//
#include <hip/hip_runtime.h>
#include <hip/hip_bf16.h>

#define NN 50000
#define NE 800000
#define NG 512
#define F0 92
#define FF 64
#define NB 41
#define HH 128
#define NBLK_SCAN 196          // ceil(NN/256)
#define NBATCH (NE / 64)
#define WBSZ (2 * 8 * 64 * 8)  // per-conv packed edge-weight elements (ushort)

typedef __attribute__((ext_vector_type(4))) float f32x4;
typedef __attribute__((ext_vector_type(8))) short bf16x8;

__device__ __forceinline__ float softplusf(float x) {
    return fmaxf(x, 0.f) + __logf(1.f + __expf(-fabsf(x)));
}
__device__ __forceinline__ float sigmoidf(float x) {
    return __fdividef(1.f, 1.f + __expf(-x));
}
__device__ __forceinline__ ushort f2bf(float v) {
    __hip_bfloat16 b = __float2bfloat16(v);   // RTN
    return *reinterpret_cast<ushort*>(&b);
}

// ---------------- sort-by-src + bf16 fragment packing ----------------

__global__ __launch_bounds__(256) void hist_kernel(const int* __restrict__ ei,
                                                   int* __restrict__ cnt)
{
    for (int e = blockIdx.x * 256 + threadIdx.x; e < NE; e += gridDim.x * 256)
        atomicAdd(&cnt[ei[e]], 1);
}

__global__ __launch_bounds__(256) void scan1_kernel(const int* __restrict__ cnt,
                                                    int* __restrict__ bsum)
{
    __shared__ int sd[256];
    const int t = threadIdx.x;
    const int idx = blockIdx.x * 256 + t;
    sd[t] = (idx < NN) ? cnt[idx] : 0;
    __syncthreads();
    for (int s = 128; s > 0; s >>= 1) {
        if (t < s) sd[t] += sd[t + s];
        __syncthreads();
    }
    if (t == 0) bsum[blockIdx.x] = sd[0];
}

__global__ __launch_bounds__(256) void scan2_kernel(int* __restrict__ bsum)
{
    __shared__ int sd[256];
    const int t = threadIdx.x;
    const int v = (t < NBLK_SCAN) ? bsum[t] : 0;
    sd[t] = v;
    __syncthreads();
    for (int off = 1; off < 256; off <<= 1) {
        int a = (t >= off) ? sd[t - off] : 0;
        __syncthreads();
        sd[t] += a;
        __syncthreads();
    }
    if (t < NBLK_SCAN) bsum[t] = sd[t] - v;   // exclusive
}

__global__ __launch_bounds__(256) void scan3_kernel(const int* __restrict__ cnt,
                                                    const int* __restrict__ bsum,
                                                    int* __restrict__ cursor)
{
    __shared__ int sd[256];
    const int t = threadIdx.x;
    const int idx = blockIdx.x * 256 + t;
    const int v = (idx < NN) ? cnt[idx] : 0;
    sd[t] = v;
    __syncthreads();
    for (int off = 1; off < 256; off <<= 1) {
        int a = (t >= off) ? sd[t - off] : 0;
        __syncthreads();
        sd[t] += a;
        __syncthreads();
    }
    if (idx < NN) cursor[idx] = bsum[blockIdx.x] + sd[t] - v;
}

// phase 1: one 16B record per edge at its sorted position (minimal scattered bytes)
__global__ __launch_bounds__(256) void scatter_kernel(const int* __restrict__ ei,
                                                      int* __restrict__ cursor,
                                                      int4* __restrict__ esd)
{
    for (int e = blockIdx.x * 256 + threadIdx.x; e < NE; e += gridDim.x * 256) {
        const int s = ei[e];
        const int d = ei[NE + e];
        const int pos = atomicAdd(&cursor[s], 1);
        esd[pos] = make_int4(e, s, d, 0);
    }
}

// phase 2: gather-side bf16 A-fragment packing (writes coalesced over pos)
// eaP layout: [group][kstep][lane][j] bf16 where edge = group*16 + (pos&15),
// k = kstep*32 + (lg)*8 + j  (zero-padded k>=41)
__global__ __launch_bounds__(256) void pack_kernel(const float* __restrict__ ea,
                                                   const int4* __restrict__ esd,
                                                   ushort* __restrict__ eaP)
{
    const int pos = blockIdx.x * 256 + threadIdx.x;
    if (pos >= NE) return;
    const int e = esd[pos].x;
    const float* row = ea + (size_t)e * NB;
    const int gg = pos >> 4, rw = pos & 15;
#pragma unroll
    for (int t2 = 0; t2 < 2; ++t2)
#pragma unroll
        for (int lg = 0; lg < 4; ++lg) {
            ushort buf[8] __attribute__((aligned(16)));
#pragma unroll
            for (int j = 0; j < 8; ++j) {
                const int k = t2 * 32 + lg * 8 + j;
                buf[j] = (k < NB) ? f2bf(row[k]) : (ushort)0;
            }
            *(int4*)&eaP[(((size_t)gg * 2 + t2) * 64 + lg * 16 + rw) * 8] =
                *(const int4*)buf;
        }
}

// packed B-fragments: wB[conv][kstep][ntile][lane][j] bf16
// B[k][col]: k = kstep*32 + (lane>>4)*8 + j, col = ntile*16 + (lane&15)
// ntile 0..3 -> gate (Wf), 4..7 -> core (Ws)
__global__ __launch_bounds__(256) void prep_kernel(
    const float* __restrict__ lnfW, const float* __restrict__ lnsW,
    ushort* __restrict__ wB)
{
    const int total = 3 * WBSZ;
    for (int idx = blockIdx.x * 256 + threadIdx.x; idx < total; idx += gridDim.x * 256) {
        const int j = idx & 7;
        const int lane = (idx >> 3) & 63;
        const int nt = (idx >> 9) & 7;
        const int t2 = (idx >> 12) & 1;
        const int i = idx >> 13;
        const int k = t2 * 32 + (lane >> 4) * 8 + j;
        const int col = (nt & 3) * 16 + (lane & 15);
        const float* W = (nt < 4 ? lnfW : lnsW) + (size_t)i * 169 * FF;
        wB[idx] = (k < NB) ? f2bf(W[(2 * FF + k) * FF + col]) : (ushort)0;
    }
}

// ---------------- network ----------------

// h = x @ embW + embb, fused column stats for bn1 of conv0
__global__ __launch_bounds__(256) void emb_kernel(
    const float* __restrict__ x, const float* __restrict__ W,
    const float* __restrict__ bias, float* __restrict__ h,
    float* __restrict__ stats0)
{
    __shared__ float sx[4][F0];
    __shared__ float sdr[2][4][FF];
    const int lane = threadIdx.x & 63;
    const int w = threadIdx.x >> 6;
    float wr[F0];
#pragma unroll
    for (int k = 0; k < F0; ++k) wr[k] = W[k * FF + lane];
    const float bv = bias[lane];
    float s = 0.f, s2 = 0.f;
    const int nit = NN / 4;
    for (int it = blockIdx.x; it < nit; it += gridDim.x) {
        const int n = it * 4 + w;
        if (lane < 46) {
            sx[w][lane * 2]     = x[n * F0 + lane * 2];
            sx[w][lane * 2 + 1] = x[n * F0 + lane * 2 + 1];
        }
        __syncthreads();
        float acc = bv;
#pragma unroll
        for (int k4 = 0; k4 < F0 / 4; ++k4) {
            float4 q = *(const float4*)&sx[w][k4 * 4];
            acc = fmaf(q.x, wr[k4 * 4 + 0], acc);
            acc = fmaf(q.y, wr[k4 * 4 + 1], acc);
            acc = fmaf(q.z, wr[k4 * 4 + 2], acc);
            acc = fmaf(q.w, wr[k4 * 4 + 3], acc);
        }
        h[n * FF + lane] = acc;
        s += acc;
        s2 = fmaf(acc, acc, s2);
        __syncthreads();
    }
    sdr[0][w][lane] = s;
    sdr[1][w][lane] = s2;
    __syncthreads();
    if (threadIdx.x < FF) {
        const int f = threadIdx.x;
        atomicAdd(&stats0[f],      sdr[0][0][f] + sdr[0][1][f] + sdr[0][2][f] + sdr[0][3][f]);
        atomicAdd(&stats0[FF + f], sdr[1][0][f] + sdr[1][1][f] + sdr[1][2][f] + sdr[1][3][f]);
    }
}

// column sums / sumsq (used for agg / bn2)
__global__ __launch_bounds__(256) void stats_kernel(
    const float* __restrict__ src, float* __restrict__ stats)
{
    __shared__ float sd[2][4][FF];
    const int f = threadIdx.x & 63;
    const int r = threadIdx.x >> 6;
    float s = 0.f, s2 = 0.f;
    for (int n = blockIdx.x * 4 + r; n < NN; n += gridDim.x * 4) {
        float v = src[n * FF + f];
        s += v;
        s2 = fmaf(v, v, s2);
    }
    sd[0][r][f] = s;
    sd[1][r][f] = s2;
    __syncthreads();
    if (threadIdx.x < FF) {
        atomicAdd(&stats[f],      sd[0][0][f] + sd[0][1][f] + sd[0][2][f] + sd[0][3][f]);
        atomicAdd(&stats[FF + f], sd[1][0][f] + sd[1][1][f] + sd[1][2][f] + sd[1][3][f]);
    }
}

__global__ void finalize_kernel(const float* __restrict__ g, const float* __restrict__ b,
                                float* __restrict__ stats)
{
    const int f = threadIdx.x;
    const float inv = 1.f / (float)NN;
    float mean = stats[f] * inv;
    float var = stats[FF + f] * inv - mean * mean;
    float rstd = rsqrtf(var + 1e-5f);
    float A = rstd * g[f];
    stats[2 * FF + f] = A;
    stats[3 * FF + f] = fmaf(-mean, A, b[f]);
}

// xn = bn1(h); pS[n*128+2f+{0,1}] = xn@{Wf,Ws}_src + {bf,bs}; pD likewise (dst rows)
__global__ __launch_bounds__(256) void node_kernel(
    const float* __restrict__ h, const float* __restrict__ stats,
    const float* __restrict__ Wf, const float* __restrict__ Ws,
    const float* __restrict__ bf, const float* __restrict__ bs,
    float* __restrict__ xn, float* __restrict__ pS, float* __restrict__ pD)
{
    __shared__ float sx[4][FF];
    const int lane = threadIdx.x & 63;
    const int w = threadIdx.x >> 6;
    const float* W = (w < 2) ? Wf : Ws;
    const int rowbase = (w & 1) * FF;
    float wr[FF];
#pragma unroll
    for (int k = 0; k < FF; ++k) wr[k] = W[(rowbase + k) * FF + lane];
    const float A = stats[2 * FF + lane];
    const float B = stats[3 * FF + lane];
    float bias = 0.f;
    if (w == 0) bias = bf[lane];
    if (w == 2) bias = bs[lane];
    float* outp = ((w & 1) ? pD : pS) + ((w >> 1) & 1);
    for (int n = blockIdx.x; n < NN; n += gridDim.x) {
        const float xv = fmaf(h[n * FF + lane], A, B);
        if (w == 0) xn[n * FF + lane] = xv;
        sx[w][lane] = xv;
        __syncthreads();
        float acc = bias;
#pragma unroll
        for (int k4 = 0; k4 < FF / 4; ++k4) {
            float4 q = *(const float4*)&sx[w][k4 * 4];
            acc = fmaf(q.x, wr[k4 * 4 + 0], acc);
            acc = fmaf(q.y, wr[k4 * 4 + 1], acc);
            acc = fmaf(q.z, wr[k4 * 4 + 2], acc);
            acc = fmaf(q.w, wr[k4 * 4 + 3], acc);
        }
        outp[(size_t)n * 128 + 2 * lane] = acc;
        __syncthreads();
    }
}

// MFMA edge kernel: 64 sorted edges per wave-batch, 4 groups of 16 (M=16).
// gate/core via v_mfma_f32_16x16x32_bf16, K=64 in 2 steps. Epilogue adds fp32
// node projections, m=sig*softplus, stage to LDS, segmented sum over sorted
// src runs, per-run-head atomicAdd.
__global__ __launch_bounds__(256) __attribute__((amdgpu_waves_per_eu(4, 4)))
void edge_kernel(const ushort* __restrict__ eaP, const int4* __restrict__ esd,
                 const ushort* __restrict__ wB,
                 const float* __restrict__ pS, const float* __restrict__ pD,
                 float* __restrict__ agg)
{
    __shared__ ushort wlds[WBSZ];           // 16 KB packed B-fragments
    __shared__ float  mld[4][64 * 17 + 4];  // per-wave m staging
    __shared__ int    sld[4][64];
    __shared__ int    dld[4][64];
    const int t = threadIdx.x, lane = t & 63, w = t >> 6;
    for (int i = t; i < WBSZ / 8; i += 256)
        ((int4*)wlds)[i] = ((const int4*)wB)[i];
    __syncthreads();
    const int le = lane >> 4, lf = lane & 15;
    const int nw = (gridDim.x * 256) >> 6;
    const int gw = (blockIdx.x * 256 + t) >> 6;

    for (int b = gw; b < NBATCH; b += nw) {
        const int pos = b * 64 + lane;
        const int4 rec = esd[pos];
        sld[w][lane] = rec.y;
        dld[w][lane] = rec.z;
        bf16x8 af[4][2];
#pragma unroll
        for (int g = 0; g < 4; ++g)
#pragma unroll
            for (int t2 = 0; t2 < 2; ++t2)
                af[g][t2] = *(const bf16x8*)&eaP[(((size_t)(b * 4 + g) * 2 + t2) * 64 + lane) * 8];

#pragma unroll
        for (int p = 0; p < 4; ++p) {
            const bf16x8 bG0 = *(const bf16x8*)&wlds[((0 * 8 + p) * 64 + lane) * 8];
            const bf16x8 bG1 = *(const bf16x8*)&wlds[((1 * 8 + p) * 64 + lane) * 8];
            const bf16x8 bC0 = *(const bf16x8*)&wlds[((0 * 8 + p + 4) * 64 + lane) * 8];
            const bf16x8 bC1 = *(const bf16x8*)&wlds[((1 * 8 + p + 4) * 64 + lane) * 8];
            const int f = p * 16 + lf;
#pragma unroll
            for (int g = 0; g < 4; ++g) {
                f32x4 aG = {0.f, 0.f, 0.f, 0.f}, aC = {0.f, 0.f, 0.f, 0.f};
                aG = __builtin_amdgcn_mfma_f32_16x16x32_bf16(af[g][0], bG0, aG, 0, 0, 0);
                aG = __builtin_amdgcn_mfma_f32_16x16x32_bf16(af[g][1], bG1, aG, 0, 0, 0);
                aC = __builtin_amdgcn_mfma_f32_16x16x32_bf16(af[g][0], bC0, aC, 0, 0, 0);
                aC = __builtin_amdgcn_mfma_f32_16x16x32_bf16(af[g][1], bC1, aC, 0, 0, 0);
                const int eb = g * 16 + le * 4;   // C/D row = 4*(lane>>4)+r
#pragma unroll
                for (int r = 0; r < 4; ++r) {
                    const int eidx = eb + r;
                    const int sv = sld[w][eidx];
                    const int dv = dld[w][eidx];
                    const float2 s2 = *(const float2*)(pS + (size_t)sv * 128 + 2 * f);
                    const float2 d2 = *(const float2*)(pD + (size_t)dv * 128 + 2 * f);
                    mld[w][eidx * 17 + lf] =
                        sigmoidf(aG[r] + s2.x + d2.x) * softplusf(aC[r] + s2.y + d2.y);
                }
            }
            const int f0 = p * 16;
            for (int s = 0; s < 16; ++s) {
                const int eidx = s * 4 + le;
                float v = mld[w][eidx * 17 + lf];
                const int sA = sld[w][eidx];
                const int sB = (le <= 2) ? sld[w][eidx + 1] : -1;
                const int sC = (le <= 1) ? sld[w][eidx + 2] : -1;
                const float t1 = __shfl_down(v, 16, 64);
                if (sB == sA) v += t1;
                const float t2v = __shfl_down(v, 32, 64);
                if (sC == sA) v += t2v;
                const bool head = (le == 0) || (sld[w][eidx - 1] != sA);
                if (head) unsafeAtomicAdd(&agg[(size_t)sA * FF + f0 + lf], v);
            }
        }
    }
}

// h = softplus(bn2(agg) + xn); fused stats for next conv's bn1; last conv pools
__global__ __launch_bounds__(256) void update_kernel(
    const float* __restrict__ agg, const float* __restrict__ xn,
    const float* __restrict__ stats, float* __restrict__ h,
    const int* __restrict__ batch, float* __restrict__ pool,
    float* __restrict__ pcnt, float* __restrict__ statsNext, const int do_pool)
{
    __shared__ float sdr[2][4][FF];
    float s = 0.f, s2 = 0.f;
    const int total = NN * FF;
    for (int idx = blockIdx.x * blockDim.x + threadIdx.x; idx < total;
         idx += gridDim.x * blockDim.x) {
        const int f = idx & 63;
        const int n = idx >> 6;
        const float A = stats[2 * FF + f];
        const float B = stats[3 * FF + f];
        const float v = softplusf(fmaf(agg[idx], A, B) + xn[idx]);
        if (do_pool) {
            const int g = batch[n];
            unsafeAtomicAdd(&pool[g * FF + f], v);
            if (f == 0) unsafeAtomicAdd(&pcnt[g], 1.f);
        } else {
            h[idx] = v;
            s += v;
            s2 = fmaf(v, v, s2);
        }
    }
    if (!do_pool) {
        const int f = threadIdx.x & 63, r = threadIdx.x >> 6;
        sdr[0][r][f] = s;
        sdr[1][r][f] = s2;
        __syncthreads();
        if (threadIdx.x < FF) {
            atomicAdd(&statsNext[f],      sdr[0][0][f] + sdr[0][1][f] + sdr[0][2][f] + sdr[0][3][f]);
            atomicAdd(&statsNext[FF + f], sdr[1][0][f] + sdr[1][1][f] + sdr[1][2][f] + sdr[1][3][f]);
        }
    }
}

__global__ __launch_bounds__(128) void readout_kernel(
    const float* __restrict__ pool, const float* __restrict__ pcnt,
    const float* __restrict__ fc1W, const float* __restrict__ fc1b,
    const float* __restrict__ outW, const float* __restrict__ outb,
    float* __restrict__ out)
{
    __shared__ float sp[FF];
    __shared__ float red[2];
    const int g = blockIdx.x;
    const int t = threadIdx.x;
    if (t < FF) {
        const float c = fmaxf(pcnt[g], 1.f);
        sp[t] = softplusf(pool[g * FF + t] / c);
    }
    __syncthreads();
    float a = fc1b[t];
#pragma unroll
    for (int k = 0; k < FF; ++k) a = fmaf(sp[k], fc1W[k * HH + t], a);
    float o = softplusf(a) * outW[t];
#pragma unroll
    for (int off = 32; off > 0; off >>= 1) o += __shfl_down(o, off, 64);
    if ((t & 63) == 0) red[t >> 6] = o;
    __syncthreads();
    if (t == 0) out[g] = red[0] + red[1] + outb[0];
}

extern "C" void kernel_launch(void* const* d_in, const int* in_sizes, int n_in,
                              void* d_out, int out_size, void* d_ws, size_t ws_size,
                              hipStream_t stream)
{
    const float* x     = (const float*)d_in[0];
    const int*   ei    = (const int*)  d_in[1];
    const float* ea    = (const float*)d_in[2];
    const int*   batch = (const int*)  d_in[3];
    const float* embW  = (const float*)d_in[4];
    const float* embb  = (const float*)d_in[5];
    const float* bn1g  = (const float*)d_in[6];
    const float* bn1b  = (const float*)d_in[7];
    const float* bn2g  = (const float*)d_in[8];
    const float* bn2b  = (const float*)d_in[9];
    const float* lnfW  = (const float*)d_in[10];
    const float* lnfb  = (const float*)d_in[11];
    const float* lnsW  = (const float*)d_in[12];
    const float* lnsb  = (const float*)d_in[13];
    const float* fc1W  = (const float*)d_in[14];
    const float* fc1b  = (const float*)d_in[15];
    const float* outW  = (const float*)d_in[16];
    const float* outb  = (const float*)d_in[17];

    float* ws      = (float*)d_ws;
    float* h       = ws;
    float* xn      = h   + (size_t)NN * FF;
    float* pS      = xn  + (size_t)NN * FF;      // [NN][128] interleaved gate/core
    float* pD      = pS  + (size_t)NN * 128;
    float* agg     = pD  + (size_t)NN * 128;
    float* pool    = agg + (size_t)NN * FF;
    float* pcnt    = pool + (size_t)NG * FF;
    float* statsB1 = pcnt + NG;                  // 3 x 256
    float* statsB2 = statsB1 + 3 * 256;          // 3 x 256
    int*   cnt     = (int*)(statsB2 + 3 * 256);  // NN
    int*   cursor  = cnt + NN;                   // NN
    int*   bsum    = cursor + NN;                // 256 (+pad to align 16B)
    int4*  esd     = (int4*)(bsum + 256);        // NE x 16B
    ushort* wB     = (ushort*)(esd + NE);        // 3 * WBSZ
    ushort* eaP    = wB + 3 * WBSZ;              // NE * 64 bf16

    // zero: cnt + (pool, pcnt, stats) regions
    hipMemsetAsync(cnt, 0, NN * sizeof(int), stream);
    hipMemsetAsync(pool, 0, (NG * FF + NG + 6 * 256) * sizeof(float), stream);

    hist_kernel<<<2048, 256, 0, stream>>>(ei, cnt);
    scan1_kernel<<<NBLK_SCAN, 256, 0, stream>>>(cnt, bsum);
    scan2_kernel<<<1, 256, 0, stream>>>(bsum);
    scan3_kernel<<<NBLK_SCAN, 256, 0, stream>>>(cnt, bsum, cursor);
    scatter_kernel<<<2048, 256, 0, stream>>>(ei, cursor, esd);
    pack_kernel<<<(NE + 255) / 256, 256, 0, stream>>>(ea, esd, eaP);
    prep_kernel<<<96, 256, 0, stream>>>(lnfW, lnsW, wB);
    emb_kernel<<<1024, 256, 0, stream>>>(x, embW, embb, h, statsB1);

    for (int i = 0; i < 3; ++i) {
        const float* Wf  = lnfW + (size_t)i * 169 * FF;
        const float* Wsp = lnsW + (size_t)i * 169 * FF;
        float* s1 = statsB1 + (size_t)i * 256;
        float* s2 = statsB2 + (size_t)i * 256;
        finalize_kernel<<<1, 64, 0, stream>>>(bn1g + i * FF, bn1b + i * FF, s1);
        node_kernel<<<1024, 256, 0, stream>>>(h, s1, Wf, Wsp,
                                              lnfb + i * FF, lnsb + i * FF, xn, pS, pD);
        hipMemsetAsync(agg, 0, (size_t)NN * FF * sizeof(float), stream);
        edge_kernel<<<1024, 256, 0, stream>>>(eaP, esd, wB + (size_t)i * WBSZ,
                                              pS, pD, agg);
        stats_kernel<<<256, 256, 0, stream>>>(agg, s2);
        finalize_kernel<<<1, 64, 0, stream>>>(bn2g + i * FF, bn2b + i * FF, s2);
        update_kernel<<<2048, 256, 0, stream>>>(agg, xn, s2, h, batch, pool, pcnt,
                                                statsB1 + (size_t)(i + 1 < 3 ? i + 1 : 0) * 256,
                                                (i == 2) ? 1 : 0);
    }
    readout_kernel<<<NG, HH, 0, stream>>>(pool, pcnt, fc1W, fc1b, outW, outb, (float*)d_out);
}